// Round 1
// 1303.044 us; speedup vs baseline: 1.1013x; 1.1013x over previous
//
#include <hip/hip_runtime.h>
#include <math.h>

typedef _Float16 h16;
typedef __attribute__((ext_vector_type(8))) _Float16 half8;  // 8 fp16 = 4 VGPRs (MFMA A/B frag)
typedef __attribute__((ext_vector_type(4))) float float4v;   // MFMA C/D frag

// Problem constants
#define BB 16
#define NN 4096
#define KK 64
#define DD 1024
#define HH 8

// ---------------------------------------------------------------------------
// Generic NT GEMM (legacy 128-class, used for the small/medium GEMMs):
// C[M,N] = scale * (A[M,Kd] · B[N,Kd]^T) + bias[n] (+gelu) + resid
// ---------------------------------------------------------------------------
template<int BM, int BN, int WM, int WN, bool SWAP>
__global__ __launch_bounds__(256)
void gemm_nt(const h16* __restrict__ A, const h16* __restrict__ B,
             float* Cf, h16* Ch,
             const float* __restrict__ bias, const float* resid,
             float scale, int Kd, int lda, int ldb, int ldc,
             long sA, long sB, long sC, int act)
{
  constexpr int BK = 32;
  constexpr int WAVES_N = BN / WN;
  constexpr int TM = WM / 16, TN = WN / 16;
  __shared__ alignas(16) h16 Ast[BM * BK];
  __shared__ alignas(16) h16 Bst[BN * BK];
  const int tid  = threadIdx.x;
  const int lane = tid & 63, wave = tid >> 6;
  const int wm = wave / WAVES_N, wn = wave % WAVES_N;
  const int bn = SWAP ? blockIdx.y : blockIdx.x;
  const int bm = SWAP ? blockIdx.x : blockIdx.y;
  const int bz = blockIdx.z;
  const h16* Ab = A + (long)bz * sA;
  const h16* Bb = B + (long)bz * sB;
  const int rowA0 = bm * BM, rowB0 = bn * BN;
  const int lrow = lane >> 2;
  const int lcol = ((lane & 3) ^ (lrow & 3)) * 8;   // swizzled k-group to fetch

  float4v acc[TM][TN];
  const float4v fzero = {0.f, 0.f, 0.f, 0.f};
  for (int i = 0; i < TM; i++)
    for (int j = 0; j < TN; j++) acc[i][j] = fzero;

  for (int k0 = 0; k0 < Kd; k0 += BK) {
    __syncthreads();
    for (int c = wave; c < BM/16; c += 4) {
      const h16* g = Ab + (long)(rowA0 + c*16 + lrow) * lda + (k0 + lcol);
      __builtin_amdgcn_global_load_lds((__attribute__((address_space(1))) const void*)g,
          (__attribute__((address_space(3))) void*)(Ast + c*512), 16, 0, 0);
    }
    for (int c = wave; c < BN/16; c += 4) {
      const h16* g = Bb + (long)(rowB0 + c*16 + lrow) * ldb + (k0 + lcol);
      __builtin_amdgcn_global_load_lds((__attribute__((address_space(1))) const void*)g,
          (__attribute__((address_space(3))) void*)(Bst + c*512), 16, 0, 0);
    }
    __syncthreads();

    const int fr = lane & 15;
    const int sw = (((lane >> 4) ^ (fr & 3)) * 8);
    half8 af[TM], bfr[TN];
    #pragma unroll
    for (int t = 0; t < TM; t++)
      af[t] = *(const half8*)(Ast + (wm*WM + t*16 + fr)*BK + sw);
    #pragma unroll
    for (int u = 0; u < TN; u++)
      bfr[u] = *(const half8*)(Bst + (wn*WN + u*16 + fr)*BK + sw);
    #pragma unroll
    for (int t = 0; t < TM; t++)
      #pragma unroll
      for (int u = 0; u < TN; u++)
        acc[t][u] = __builtin_amdgcn_mfma_f32_16x16x32_f16(af[t], bfr[u], acc[t][u], 0, 0, 0);
  }

  const int r0 = rowA0 + wm*WM + (lane >> 4) * 4;
  const int c0 = rowB0 + wn*WN + (lane & 15);
  float* Cfb = Cf ? Cf + (long)bz * sC : (float*)0;
  h16*   Chb = Ch ? Ch + (long)bz * sC : (h16*)0;
  const float* rb = resid ? resid + (long)bz * sC : (const float*)0;
  #pragma unroll
  for (int t = 0; t < TM; t++) {
    #pragma unroll
    for (int u = 0; u < TN; u++) {
      const int col = c0 + u*16;
      const float bv = bias ? bias[col] : 0.f;
      #pragma unroll
      for (int r = 0; r < 4; r++) {
        const long idx = (long)(r0 + t*16 + r) * ldc + col;
        float vv = acc[t][u][r] * scale + bv;
        if (act == 1) vv = 0.5f * vv * (1.f + erff(vv * 0.70710678118654752f));
        if (rb) vv += rb[idx];
        if (Cfb) Cfb[idx] = vv;
        if (Chb) Chb[idx] = (h16)vv;
      }
    }
  }
}

// ---------------------------------------------------------------------------
// 256x256 / BK=64 8-phase counted-vmcnt NT GEMM (fp16 in, fp16 out, no bias).
// 512 threads = 8 waves (2M x 4N), per-wave 128x64 output, acc[8][4].
// LDS 128 KiB: 2 K-tile buffers x (A 256x64 + B 256x64) fp16.
// Schedule per iteration (tiles T=buf0, T+1=buf1), 8 phases:
//   P1: read A0+B0(T,buf0)[12 ds_read] | stage T+1.h1 | bar | MFMA Q00 | bar
//   P2: read B1            [ 4]        | stage T+1.h2 | bar | MFMA Q01 | bar
//   P3: read A1            [ 8]        | stage T+1.h3 | bar | MFMA Q11 | bar
//   P4:                                | stage T+2.h0 | bar | MFMA Q10 | vmcnt(2) | bar
//   P5..P8: same on tile T+1 (buf1), staging T+2.h1..h3, T+3.h0, vmcnt(2) at P8.
// Race-freedom: buf0 fully read by P3's end-barrier -> T+2 (buf0) staged P4-P7;
// buf1 fully read by P7 -> T+3 (buf1) staged P8,P1',P2',P3'. vmcnt(2)+barrier at
// P4/P8 guarantees the next tile's 4 half-tiles have landed before they're read.
// LDS swizzle: 16B chunk c of row r stored at c^(r&7)  (8-chunk spread -> 2-way max).
// XCD swizzle (m204 bijective): logical-consecutive blocks land on one XCD, so
// the nInner blocks sharing an operand panel share that XCD's L2.
// ---------------------------------------------------------------------------
__device__ __forceinline__ void gld16(const h16* g, h16* l) {
  __builtin_amdgcn_global_load_lds((__attribute__((address_space(1))) const void*)g,
                                   (__attribute__((address_space(3))) void*)l, 16, 0, 0);
}

#define PH_BAR() do { asm volatile("" ::: "memory"); __builtin_amdgcn_s_barrier(); \
                      asm volatile("" ::: "memory"); } while (0)
#define WAITV2() asm volatile("s_waitcnt vmcnt(2)" ::: "memory")
#define WAITV0() asm volatile("s_waitcnt vmcnt(0)" ::: "memory")
#define MF(a, b, c) c = __builtin_amdgcn_mfma_f32_16x16x32_f16(a, b, c, 0, 0, 0)

template<bool SWAP>
__global__ __launch_bounds__(512, 2)
void gemm_nt8(const h16* __restrict__ A, const h16* __restrict__ B,
              h16* __restrict__ C, int Kd, int lda, int ldb, int ldc,
              long sA, long sB, long sC, int nInner)
{
  __shared__ alignas(16) h16 As[2][16384];   // [buf][256 rows x 64 cols]
  __shared__ alignas(16) h16 Bs[2][16384];
  const int tid  = threadIdx.x;
  const int lane = tid & 63, wv = tid >> 6;
  const int wm = wv >> 2, wn = wv & 3;
  const int fr = lane & 15, fq = lane >> 4;

  // m204 bijective XCD swizzle over flattened grid.x
  const int nwg = gridDim.x;
  const int q = nwg >> 3, r = nwg & 7;
  const int xcd = blockIdx.x & 7, lid = blockIdx.x >> 3;
  const int wg = (xcd < r ? xcd * (q + 1) : r * (q + 1) + (xcd - r) * q) + lid;
  int bm, bn;
  if (SWAP) { bm = wg % nInner; bn = wg / nInner; }   // B is the big operand
  else      { bn = wg % nInner; bm = wg / nInner; }   // A is the big operand
  const int bz = blockIdx.z;

  const h16* pA = A + (long)bz * sA + (long)(bm * 256) * lda;
  const h16* pB = B + (long)bz * sB + (long)(bn * 256) * ldb;

  // staging: one issue = 512 thr x 16B = 64 rows x 128B. thread t -> row t>>3,
  // chunk t&7; fetch swizzled global chunk (t&7)^(row&7). LDS dest is linear
  // (wave-uniform base + lane*16), matching global_load_lds HW semantics.
  const int srow = tid >> 3;
  const int scol = ((tid & 7) ^ (srow & 7)) << 3;
  const h16* stA = pA + (long)srow * lda + scol;
  const h16* stB = pB + (long)srow * ldb + scol;
  const int nt = Kd >> 6;            // K-tiles of 64; must be even (K=1024 -> 16)

  auto stage = [&](int t, int hf) {  // hf: 0,1 = A halves; 2,3 = B halves
    if (t >= nt) return;
    const int d = t & 1;
    if (hf < 2) {
      const h16* g = stA + (long)(hf * 128) * lda + t * 64;
      h16* l = &As[d][hf * 8192] + wv * 512;
      gld16(g, l);
      gld16(g + (long)64 * lda, l + 4096);
    } else {
      const h16* g = stB + (long)((hf - 2) * 128) * ldb + t * 64;
      h16* l = &Bs[d][(hf - 2) * 8192] + wv * 512;
      gld16(g, l);
      gld16(g + (long)64 * ldb, l + 4096);
    }
  };

  // frag read bases: row rr of tile, chunk kk*4+fq, swizzled ^= (rr&7)
  const int rbA = (wm * 128 + fr) * 64;
  const int rbB = (wn * 64 + fr) * 64;
  const int cs0 = ((fq)     ^ (fr & 7)) << 3;
  const int cs1 = ((4 + fq) ^ (fr & 7)) << 3;

  float4v acc[8][4];
  const float4v fzero = {0.f, 0.f, 0.f, 0.f};
  #pragma unroll
  for (int m = 0; m < 8; m++)
    #pragma unroll
    for (int n = 0; n < 4; n++) acc[m][n] = fzero;

  // prologue: tile0 fully + tile1.h0; allow tile1.h0 (2 loads) outstanding
  stage(0, 0); stage(0, 1); stage(0, 2); stage(0, 3);
  stage(1, 0);
  if (nt > 1) WAITV2(); else WAITV0();
  __builtin_amdgcn_s_barrier();
  asm volatile("" ::: "memory");

  half8 aL[4][2], aH[4][2], bL[2][2], bH[2][2];

  for (int T = 0; T < nt; T += 2) {
    // ================= tile T (buf 0) =================
    // ---- P1: Q00 ----
    #pragma unroll
    for (int m = 0; m < 4; m++) {
      aL[m][0] = *(const half8*)&As[0][rbA + m*1024 + cs0];
      aL[m][1] = *(const half8*)&As[0][rbA + m*1024 + cs1];
    }
    #pragma unroll
    for (int n = 0; n < 2; n++) {
      bL[n][0] = *(const half8*)&Bs[0][rbB + n*1024 + cs0];
      bL[n][1] = *(const half8*)&Bs[0][rbB + n*1024 + cs1];
    }
    stage(T + 1, 1);
    PH_BAR();
    __builtin_amdgcn_s_setprio(1);
    #pragma unroll
    for (int m = 0; m < 4; m++)
      #pragma unroll
      for (int n = 0; n < 2; n++) { MF(aL[m][0], bL[n][0], acc[m][n]); MF(aL[m][1], bL[n][1], acc[m][n]); }
    __builtin_amdgcn_s_setprio(0);
    PH_BAR();
    // ---- P2: Q01 ----
    #pragma unroll
    for (int n = 0; n < 2; n++) {
      bH[n][0] = *(const half8*)&Bs[0][rbB + (n+2)*1024 + cs0];
      bH[n][1] = *(const half8*)&Bs[0][rbB + (n+2)*1024 + cs1];
    }
    stage(T + 1, 2);
    PH_BAR();
    __builtin_amdgcn_s_setprio(1);
    #pragma unroll
    for (int m = 0; m < 4; m++)
      #pragma unroll
      for (int n = 0; n < 2; n++) { MF(aL[m][0], bH[n][0], acc[m][n+2]); MF(aL[m][1], bH[n][1], acc[m][n+2]); }
    __builtin_amdgcn_s_setprio(0);
    PH_BAR();
    // ---- P3: Q11 ----
    #pragma unroll
    for (int m = 0; m < 4; m++) {
      aH[m][0] = *(const half8*)&As[0][rbA + (m+4)*1024 + cs0];
      aH[m][1] = *(const half8*)&As[0][rbA + (m+4)*1024 + cs1];
    }
    stage(T + 1, 3);
    PH_BAR();
    __builtin_amdgcn_s_setprio(1);
    #pragma unroll
    for (int m = 0; m < 4; m++)
      #pragma unroll
      for (int n = 0; n < 2; n++) { MF(aH[m][0], bH[n][0], acc[m+4][n+2]); MF(aH[m][1], bH[n][1], acc[m+4][n+2]); }
    __builtin_amdgcn_s_setprio(0);
    PH_BAR();
    // ---- P4: Q10 ----
    stage(T + 2, 0);
    PH_BAR();
    __builtin_amdgcn_s_setprio(1);
    #pragma unroll
    for (int m = 0; m < 4; m++)
      #pragma unroll
      for (int n = 0; n < 2; n++) { MF(aH[m][0], bL[n][0], acc[m+4][n]); MF(aH[m][1], bL[n][1], acc[m+4][n]); }
    __builtin_amdgcn_s_setprio(0);
    if (T + 2 < nt) WAITV2(); else WAITV0();   // tile T+1 fully landed
    PH_BAR();

    // ================= tile T+1 (buf 1) =================
    // ---- P5: Q00 ----
    #pragma unroll
    for (int m = 0; m < 4; m++) {
      aL[m][0] = *(const half8*)&As[1][rbA + m*1024 + cs0];
      aL[m][1] = *(const half8*)&As[1][rbA + m*1024 + cs1];
    }
    #pragma unroll
    for (int n = 0; n < 2; n++) {
      bL[n][0] = *(const half8*)&Bs[1][rbB + n*1024 + cs0];
      bL[n][1] = *(const half8*)&Bs[1][rbB + n*1024 + cs1];
    }
    stage(T + 2, 1);
    PH_BAR();
    __builtin_amdgcn_s_setprio(1);
    #pragma unroll
    for (int m = 0; m < 4; m++)
      #pragma unroll
      for (int n = 0; n < 2; n++) { MF(aL[m][0], bL[n][0], acc[m][n]); MF(aL[m][1], bL[n][1], acc[m][n]); }
    __builtin_amdgcn_s_setprio(0);
    PH_BAR();
    // ---- P6: Q01 ----
    #pragma unroll
    for (int n = 0; n < 2; n++) {
      bH[n][0] = *(const half8*)&Bs[1][rbB + (n+2)*1024 + cs0];
      bH[n][1] = *(const half8*)&Bs[1][rbB + (n+2)*1024 + cs1];
    }
    stage(T + 2, 2);
    PH_BAR();
    __builtin_amdgcn_s_setprio(1);
    #pragma unroll
    for (int m = 0; m < 4; m++)
      #pragma unroll
      for (int n = 0; n < 2; n++) { MF(aL[m][0], bH[n][0], acc[m][n+2]); MF(aL[m][1], bH[n][1], acc[m][n+2]); }
    __builtin_amdgcn_s_setprio(0);
    PH_BAR();
    // ---- P7: Q11 ----
    #pragma unroll
    for (int m = 0; m < 4; m++) {
      aH[m][0] = *(const half8*)&As[1][rbA + (m+4)*1024 + cs0];
      aH[m][1] = *(const half8*)&As[1][rbA + (m+4)*1024 + cs1];
    }
    stage(T + 2, 3);
    PH_BAR();
    __builtin_amdgcn_s_setprio(1);
    #pragma unroll
    for (int m = 0; m < 4; m++)
      #pragma unroll
      for (int n = 0; n < 2; n++) { MF(aH[m][0], bH[n][0], acc[m+4][n+2]); MF(aH[m][1], bH[n][1], acc[m+4][n+2]); }
    __builtin_amdgcn_s_setprio(0);
    PH_BAR();
    // ---- P8: Q10 ----
    stage(T + 3, 0);
    PH_BAR();
    __builtin_amdgcn_s_setprio(1);
    #pragma unroll
    for (int m = 0; m < 4; m++)
      #pragma unroll
      for (int n = 0; n < 2; n++) { MF(aH[m][0], bL[n][0], acc[m+4][n]); MF(aH[m][1], bL[n][1], acc[m+4][n]); }
    __builtin_amdgcn_s_setprio(0);
    if (T + 3 < nt) WAITV2(); else WAITV0();   // tile T+2 fully landed
    PH_BAR();
  }

  // epilogue: C/D layout col=lane&15, row=(lane>>4)*4+reg
  h16* Cb = C + (long)bz * sC;
  const int r0 = bm * 256 + wm * 128 + fq * 4;
  const int c0 = bn * 256 + wn * 64 + fr;
  #pragma unroll
  for (int m = 0; m < 8; m++)
    #pragma unroll
    for (int n = 0; n < 4; n++)
      #pragma unroll
      for (int rr = 0; rr < 4; rr++)
        Cb[(long)(r0 + m*16 + rr) * ldc + (c0 + n*16)] = (h16)acc[m][n][rr];
}

// ---------------------------------------------------------------------------
// Fused attn = q·k^T * scale, then softmax over the SLOT axis (rows), write
// aw fp16. BM=64 covers ALL slots -> column softmax is block-local.
// ---------------------------------------------------------------------------
__global__ __launch_bounds__(256)
void attn_softmax(const h16* __restrict__ q, const h16* __restrict__ k,
                  h16* __restrict__ aw)
{
  constexpr int BK = 32;
  __shared__ alignas(16) h16 Ast[64 * BK];
  __shared__ alignas(16) h16 Bst[128 * BK];
  const int tid = threadIdx.x;
  const int lane = tid & 63, wave = tid >> 6;
  const int bn = blockIdx.x, bz = blockIdx.z;
  const h16* Ab = q + (long)bz * (KK * DD);
  const h16* Bb = k + (long)bz * ((long)NN * DD);
  const int rowB0 = bn * 128;
  const int lrow = lane >> 2;
  const int lcol = ((lane & 3) ^ (lrow & 3)) * 8;

  float4v acc[4][2];
  const float4v fzero = {0.f, 0.f, 0.f, 0.f};
  for (int i = 0; i < 4; i++)
    for (int j = 0; j < 2; j++) acc[i][j] = fzero;

  for (int k0 = 0; k0 < DD; k0 += BK) {
    __syncthreads();
    if (wave < 4) {
      const h16* g = Ab + (long)(wave*16 + lrow) * DD + (k0 + lcol);
      __builtin_amdgcn_global_load_lds((__attribute__((address_space(1))) const void*)g,
          (__attribute__((address_space(3))) void*)(Ast + wave*512), 16, 0, 0);
    }
    for (int c = wave; c < 8; c += 4) {
      const h16* g = Bb + (long)(rowB0 + c*16 + lrow) * DD + (k0 + lcol);
      __builtin_amdgcn_global_load_lds((__attribute__((address_space(1))) const void*)g,
          (__attribute__((address_space(3))) void*)(Bst + c*512), 16, 0, 0);
    }
    __syncthreads();
    const int fr = lane & 15;
    const int sw = (((lane >> 4) ^ (fr & 3)) * 8);
    half8 af[4], bfr[2];
    #pragma unroll
    for (int t = 0; t < 4; t++)
      af[t] = *(const half8*)(Ast + (t*16 + fr)*BK + sw);
    #pragma unroll
    for (int u = 0; u < 2; u++)
      bfr[u] = *(const half8*)(Bst + (wave*32 + u*16 + fr)*BK + sw);
    #pragma unroll
    for (int t = 0; t < 4; t++)
      #pragma unroll
      for (int u = 0; u < 2; u++)
        acc[t][u] = __builtin_amdgcn_mfma_f32_16x16x32_f16(af[t], bfr[u], acc[t][u], 0, 0, 0);
  }

  h16* awz = aw + (long)bz * ((long)KK * NN);
  #pragma unroll
  for (int u = 0; u < 2; u++) {
    float e[4][4];
    float mx = -1e30f;
    #pragma unroll
    for (int t = 0; t < 4; t++)
      #pragma unroll
      for (int r = 0; r < 4; r++) {
        e[t][r] = acc[t][u][r] * 0.03125f;
        mx = fmaxf(mx, e[t][r]);
      }
    mx = fmaxf(mx, __shfl_xor(mx, 16));
    mx = fmaxf(mx, __shfl_xor(mx, 32));
    float sum = 0.f;
    #pragma unroll
    for (int t = 0; t < 4; t++)
      #pragma unroll
      for (int r = 0; r < 4; r++) { e[t][r] = __expf(e[t][r] - mx); sum += e[t][r]; }
    sum += __shfl_xor(sum, 16);
    sum += __shfl_xor(sum, 32);
    const float rinv = 1.f / sum;
    const int col = rowB0 + wave*32 + u*16 + (lane & 15);
    #pragma unroll
    for (int t = 0; t < 4; t++)
      #pragma unroll
      for (int r = 0; r < 4; r++) {
        const int row = t*16 + (lane >> 4)*4 + r;
        awz[(long)row * NN + col] = (h16)(e[t][r] * rinv);
      }
  }
}

// ---------------------------------------------------------------------------
// LayerNorm over D=1024 (one block per row). Optional fused add (x + add).
// ---------------------------------------------------------------------------
__global__ __launch_bounds__(256)
void ln_kernel(const float* x, const float* add,
               const float* __restrict__ g, const float* __restrict__ b,
               float* outf, h16* outh)
{
  const int row = blockIdx.x, t = threadIdx.x;
  const long rb_ = (long)row * DD;
  float v[4]; float s = 0.f, s2 = 0.f;
  #pragma unroll
  for (int i = 0; i < 4; i++) {
    const int c = t + i*256;
    float xv = x[rb_ + c];
    if (add) xv += add[rb_ + c];
    v[i] = xv; s += xv; s2 += xv*xv;
  }
  #pragma unroll
  for (int off = 32; off > 0; off >>= 1) {
    s  += __shfl_down(s,  off, 64);
    s2 += __shfl_down(s2, off, 64);
  }
  __shared__ float red[8];
  const int lane = t & 63, w = t >> 6;
  if (lane == 0) { red[w] = s; red[4+w] = s2; }
  __syncthreads();
  const float S  = red[0]+red[1]+red[2]+red[3];
  const float S2 = red[4]+red[5]+red[6]+red[7];
  const float mean = S * (1.f/DD);
  const float var  = S2 * (1.f/DD) - mean*mean;
  const float rinv = rsqrtf(var + 1e-5f);
  #pragma unroll
  for (int i = 0; i < 4; i++) {
    const int c = t + i*256;
    const float y = (v[i] - mean) * rinv * g[c] + b[c];
    if (outf) outf[rb_ + c] = y;
    if (outh) outh[rb_ + c] = (h16)y;
  }
}

// Slot self-attention MHA: one block per (b,h). seq=64, dh=128. fp16 I/O.
__global__ __launch_bounds__(256)
void mha_kernel(const h16* __restrict__ qkv, h16* __restrict__ sa)
{
  const int b = blockIdx.x >> 3, h = blockIdx.x & 7;
  __shared__ h16   mk[64][128];
  __shared__ h16   mv[64][128];
  __shared__ float sc[64][64];
  const int t = threadIdx.x;
  const long base = ((long)b * 64) * (3*DD) + h * 128;
  for (int i = t; i < 64*128; i += 256) {
    const int r = i >> 7, d = i & 127;
    mk[r][d] = qkv[base + (long)r*(3*DD) + DD   + d];
    mv[r][d] = qkv[base + (long)r*(3*DD) + 2*DD + d];
  }
  __syncthreads();
  {  // scores
    const int q = t >> 2, kb2 = (t & 3) * 16;
    float accv[16];
    #pragma unroll
    for (int i = 0; i < 16; i++) accv[i] = 0.f;
    const h16* mq = qkv + base + (long)q * (3*DD);
    for (int d0 = 0; d0 < 128; d0 += 8) {
      float qr[8];
      #pragma unroll
      for (int j = 0; j < 8; j++) qr[j] = (float)mq[d0 + j];
      #pragma unroll
      for (int i = 0; i < 16; i++) {
        float sacc = 0.f;
        #pragma unroll
        for (int j = 0; j < 8; j++) sacc += qr[j] * (float)(mk[kb2+i][d0+j]);
        accv[i] += sacc;
      }
    }
    #pragma unroll
    for (int i = 0; i < 16; i++) sc[q][kb2+i] = accv[i] * 0.088388347648318447f; // 1/sqrt(128)
  }
  __syncthreads();
  if (t < 64) {  // softmax over keys, row t
    float mx = -1e30f;
    for (int i = 0; i < 64; i++) mx = fmaxf(mx, sc[t][i]);
    float sum = 0.f;
    for (int i = 0; i < 64; i++) { const float e = __expf(sc[t][i] - mx); sc[t][i] = e; sum += e; }
    const float r = 1.f / sum;
    for (int i = 0; i < 64; i++) sc[t][i] *= r;
  }
  __syncthreads();
  {  // out
    const int q = t >> 2, d0 = (t & 3) * 32;
    float o[32];
    #pragma unroll
    for (int i = 0; i < 32; i++) o[i] = 0.f;
    for (int k2 = 0; k2 < 64; k2++) {
      const float p = sc[q][k2];
      #pragma unroll
      for (int i = 0; i < 32; i++) o[i] += p * (float)(mv[k2][d0+i]);
    }
    h16* op = sa + ((long)(b*64 + q)) * DD + h*128 + d0;
    #pragma unroll
    for (int i = 0; i < 32; i++) op[i] = (h16)o[i];
  }
}

// fp32 [R,C] -> fp16 [C,R] (weight transpose+cast)
__global__ void transpose_cast(const float* __restrict__ src, h16* __restrict__ dst,
                               int R, int C)
{
  __shared__ float tile[32][33];
  const int c0 = blockIdx.x * 32, r0 = blockIdx.y * 32;
  const int tx = threadIdx.x & 31, ty = threadIdx.x >> 5;
  for (int i = ty; i < 32; i += 8) tile[i][tx] = src[(long)(r0+i)*C + c0 + tx];
  __syncthreads();
  for (int i = ty; i < 32; i += 8) dst[(long)(c0+i)*R + r0 + tx] = (h16)tile[tx][i];
}

__global__ void cast_f32_h16(const float* __restrict__ x, h16* __restrict__ y, long n)
{
  const long i = (long)blockIdx.x * 256 + threadIdx.x;
  if (i < n) y[i] = (h16)x[i];
}

// slots[b*64+k][d] = slot_init[k][d]
__global__ void init_slots(const float* __restrict__ si, float* __restrict__ S)
{
  const long i = (long)blockIdx.x * 256 + threadIdx.x;   // over 1024*1024
  const int row = (int)(i >> 10), d = (int)(i & 1023);
  S[i] = si[((row & 63) << 10) + d];
}

// ---------------------------------------------------------------------------
extern "C" void kernel_launch(void* const* d_in, const int* in_sizes, int n_in,
                              void* d_out, int out_size, void* d_ws, size_t ws_size,
                              hipStream_t stream)
{
  const float* vt        = (const float*)d_in[0];
  const float* slot_init = (const float*)d_in[1];
  const float* ln_vis_g  = (const float*)d_in[2];
  const float* ln_vis_b  = (const float*)d_in[3];
  const float* ln_sl_g   = (const float*)d_in[4];
  const float* ln_sl_b   = (const float*)d_in[5];
  const float* Wq        = (const float*)d_in[6];
  const float* Wk        = (const float*)d_in[7];
  const float* Wv        = (const float*)d_in[8];
  const float* Wo        = (const float*)d_in[9];
  const float* mha_in_w  = (const float*)d_in[10];
  const float* mha_in_b  = (const float*)d_in[11];
  const float* mha_out_w = (const float*)d_in[12];
  const float* mha_out_b = (const float*)d_in[13];
  const float* ln_sa_g   = (const float*)d_in[14];
  const float* ln_sa_b   = (const float*)d_in[15];
  const float* ln_ffn_g  = (const float*)d_in[16];
  const float* ln_ffn_b  = (const float*)d_in[17];
  const float* W1        = (const float*)d_in[18];
  const float* b1        = (const float*)d_in[19];
  const float* W2        = (const float*)d_in[20];
  const float* b2        = (const float*)d_in[21];
  float* out = (float*)d_out;

  // ---- workspace (bump allocator, 256B aligned) ----
  char* ws = (char*)d_ws;
  size_t off = 0;
  auto alloc = [&](size_t bytes) -> char* {
    char* p = ws + off; off += (bytes + 255) & ~(size_t)255; return p;
  };
  h16* wqT  = (h16*)alloc((size_t)DD*DD*2);        // [out,in]
  h16* wkT  = (h16*)alloc((size_t)DD*DD*2);
  h16* wvT  = (h16*)alloc((size_t)DD*DD*2);
  h16* woT  = (h16*)alloc((size_t)DD*DD*2);
  h16* w_in = (h16*)alloc((size_t)3*DD*DD*2);      // already [out,in]
  h16* w_ou = (h16*)alloc((size_t)DD*DD*2);
  h16* w1T  = (h16*)alloc((size_t)2*DD*DD*2);      // [2D, D]
  h16* w2T  = (h16*)alloc((size_t)2*DD*DD*2);      // [D, 2D]
  float* S      = (float*)alloc((size_t)BB*KK*DD*4);
  h16*   snb    = (h16*)alloc((size_t)BB*KK*DD*2);
  h16*   qb     = (h16*)alloc((size_t)BB*KK*DD*2);
  h16*   updb   = (h16*)alloc((size_t)BB*KK*DD*2);
  h16*   slotsb = (h16*)alloc((size_t)BB*KK*DD*2);
  h16*   sab    = (h16*)alloc((size_t)BB*KK*DD*2);
  h16*   hb     = (h16*)alloc((size_t)BB*KK*DD*2);
  h16*   g1b    = (h16*)alloc((size_t)BB*KK*2*DD*2);
  h16*   qkvh   = (h16*)alloc((size_t)BB*KK*3*DD*2);
  float* sa2    = (float*)alloc((size_t)BB*KK*DD*4);
  h16*   awb    = (h16*)alloc((size_t)BB*KK*NN*2);  // 8.4 MB
  h16*   vnb    = (h16*)alloc((size_t)BB*NN*DD*2);  // 134 MB
  h16*   kbuf   = (h16*)alloc((size_t)BB*NN*DD*2);  // 134 MB
  h16*   vT     = (h16*)alloc((size_t)BB*NN*DD*2);  // 134 MB, [B][D][N]
  (void)in_sizes; (void)n_in; (void)out_size; (void)ws_size;

  const dim3 blk(256);
  const dim3 blk8(512);
  const float* nf = nullptr;

  // ---- weight prep ----
  transpose_cast<<<dim3(32,32,1), blk, 0, stream>>>(Wq, wqT, DD, DD);
  transpose_cast<<<dim3(32,32,1), blk, 0, stream>>>(Wk, wkT, DD, DD);
  transpose_cast<<<dim3(32,32,1), blk, 0, stream>>>(Wv, wvT, DD, DD);
  transpose_cast<<<dim3(32,32,1), blk, 0, stream>>>(Wo, woT, DD, DD);
  transpose_cast<<<dim3(64,32,1), blk, 0, stream>>>(W1, w1T, DD, 2*DD);
  transpose_cast<<<dim3(32,64,1), blk, 0, stream>>>(W2, w2T, 2*DD, DD);
  cast_f32_h16<<<dim3(12288), blk, 0, stream>>>(mha_in_w, w_in, (long)3*DD*DD);
  cast_f32_h16<<<dim3(4096),  blk, 0, stream>>>(mha_out_w, w_ou, (long)DD*DD);
  init_slots<<<dim3(4096), blk, 0, stream>>>(slot_init, S);

  // ---- phase A: vn = LN(vt); k = vn@Wk  [B*N,D]; vT = (vn@Wv)^T  [B][D,N] ----
  ln_kernel<<<dim3(BB*NN), blk, 0, stream>>>(vt, nullptr, ln_vis_g, ln_vis_b, nullptr, vnb);
  // k: A=vnb big (M = B*N = 65536 folded), N=1024 -> nInner = nbn = 4
  gemm_nt8<false><<<dim3(1024,1,1), blk8, 0, stream>>>(
      vnb, wkT, kbuf, DD, DD, DD, DD, 0, 0, 0, 4);
  // vT: B=vnb big, per-batch M=1024, N=4096 -> nInner = nbm = 4
  gemm_nt8<true><<<dim3(64,1,BB), blk8, 0, stream>>>(
      wvT, vnb, vT, DD, DD, DD, NN, 0, (long)NN*DD, (long)DD*NN, 4);

  // ---- 2 slot-attention iterations ----
  for (int it = 0; it < 2; ++it) {
    ln_kernel<<<dim3(BB*KK), blk, 0, stream>>>(S, nullptr, ln_sl_g, ln_sl_b, nullptr, snb);
    gemm_nt<32,64,16,32,false><<<dim3(16,32,1), blk, 0, stream>>>(     // q = sn @ Wq
        snb, wqT, nullptr, qb, nf, nf, 1.f, DD, DD, DD, DD, 0, 0, 0, 0);
    attn_softmax<<<dim3(32,1,BB), blk, 0, stream>>>(qb, kbuf, awb);    // fused qk^T+softmax
    gemm_nt<32,64,16,32,false><<<dim3(16,2,BB), blk, 0, stream>>>(     // upd = aw · v
        awb, vT, nullptr, updb, nf, nf, 1.f, NN, NN, NN, DD,
        (long)KK*NN, (long)DD*NN, (long)KK*DD, 0);
    gemm_nt<32,64,16,32,false><<<dim3(16,32,1), blk, 0, stream>>>(     // S += upd@Wo (+fp16 copy)
        updb, woT, S, slotsb, nf, S, 1.f, DD, DD, DD, DD, 0, 0, 0, 0);
    gemm_nt<64,128,64,32,false><<<dim3(24,16,1), blk, 0, stream>>>(    // qkv = slots@Win^T + b
        slotsb, w_in, nullptr, qkvh, mha_in_b, nf, 1.f, DD, DD, DD, 3*DD, 0, 0, 0, 0);
    mha_kernel<<<dim3(BB*HH), blk, 0, stream>>>(qkvh, sab);
    gemm_nt<32,64,16,32,false><<<dim3(16,32,1), blk, 0, stream>>>(     // sa2 = sa@Wout^T + b
        sab, w_ou, sa2, nullptr, mha_out_b, nf, 1.f, DD, DD, DD, DD, 0, 0, 0, 0);
    ln_kernel<<<dim3(BB*KK), blk, 0, stream>>>(S, sa2, ln_sa_g, ln_sa_b, S, nullptr);
  }

  // ---- FFN tail: out = S + gelu(LN(S)@W1 + b1)@W2 + b2 ----
  ln_kernel<<<dim3(BB*KK), blk, 0, stream>>>(S, nullptr, ln_ffn_g, ln_ffn_b, nullptr, hb);
  gemm_nt<32,128,32,32,false><<<dim3(16,32,1), blk, 0, stream>>>(      // g1 = gelu(h@W1+b1)
      hb, w1T, nullptr, g1b, b1, nf, 1.f, DD, DD, DD, 2*DD, 0, 0, 0, 1);
  gemm_nt<32,64,16,32,false><<<dim3(16,32,1), blk, 0, stream>>>(       // out = S + g1@W2 + b2
      g1b, w2T, out, nullptr, b2, S, 1.f, 2*DD, 2*DD, 2*DD, DD, 0, 0, 0, 0);
}